// Round 16
// baseline (367.465 us; speedup 1.0000x reference)
//
#include <hip/hip_runtime.h>

typedef unsigned short bf16u;
typedef unsigned char u8;
typedef unsigned int u32;
typedef float f32x4 __attribute__((ext_vector_type(4)));
typedef short bf16x8 __attribute__((ext_vector_type(8)));

__device__ inline float sigmoidf_(float x) { return 1.f / (1.f + __expf(-x)); }
__device__ inline float b2f(bf16u u) { return __uint_as_float(((u32)u) << 16); }
__device__ inline bf16u f2b(float f) {
  u32 i = __float_as_uint(f);
  u32 r = (i + 0x7fffu + ((i >> 16) & 1u)) >> 16;
  return (bf16u)r;
}
// uint8 table codec: stored = clamp(round(v*512 + 128)); decoded = u/512 - 0.25
__device__ inline u8 enc8(float v) {
  float q = fmaf(v, 512.f, 128.5f);
  q = fminf(fmaxf(q, 0.f), 255.f);
  return (u8)(int)q;
}
__device__ inline float ub0(u32 u) { return (float)(u & 0xffu); }
__device__ inline float ub1(u32 u) { return (float)((u >> 8) & 0xffu); }
__device__ inline float ub2(u32 u) { return (float)((u >> 16) & 0xffu); }
__device__ inline float ub3(u32 u) { return (float)(u >> 24); }

// ---------------------------------------------------------------------------
// Fused prep: XX pad zero (all 4096 blocks), LSTM weight pack (b<2048),
// Vp bf16 conversion (b in [2048,2304)), uvec (b==2304).
__global__ __launch_bounds__(256) void k_prep(
    const float* __restrict__ gcn_w, const float* __restrict__ attn_w,
    const float* __restrict__ w_ih, const float* __restrict__ w_hh,
    const float* __restrict__ b_ih, const float* __restrict__ b_hh,
    bf16u* __restrict__ Vp, float* __restrict__ uvec,
    bf16u* __restrict__ WWa, bf16u* __restrict__ WWb, float* __restrict__ bsum,
    bf16u* __restrict__ XX)
{
  const int b = blockIdx.x, t = threadIdx.x;
  if (t < 59) XX[(size_t)b * 576 + 517 + t] = 0;
  if (b < 2048) {
    float wi = w_ih[b * 256 + t];
    float wh = w_hh[b * 512 + t];
    WWa[(size_t)b * 576 + t] = f2b(wi);
    WWb[(size_t)b * 576 + t] = f2b(wi + wh);
    WWb[(size_t)b * 576 + 256 + t] = f2b(wh);
    if (t < 59) WWb[(size_t)b * 576 + 517 + t] = 0;
    if (t == 0) bsum[b] = b_ih[b] + b_hh[b];
  } else if (b < 2304) {
    const int o = b - 2048;
    if (t < 128) Vp[o * 128 + t] = f2b(gcn_w[(o & 127) * 256 + ((o >> 7) << 7) + t]);
  } else if (b == 2304) {
    const int col = ((t >> 7) << 7) + (t & 127);
    float acc = 0.f;
    for (int d = 0; d < 128; ++d) acc += gcn_w[d * 256 + col] * attn_w[d];
    uvec[t] = acc;
  }
}

// ---------------------------------------------------------------------------
// pr/pe tables (uint8) via bf16 MFMA; scores post-staging from LDS.
__global__ __launch_bounds__(256) void k_pre_gemm(
    const float* __restrict__ emb, const bf16u* __restrict__ Vp,
    const float* __restrict__ uvec,
    u8* __restrict__ pr, u8* __restrict__ pe,
    float* __restrict__ srel, float* __restrict__ sent)
{
  const int t = threadIdx.x;
  const int row0 = blockIdx.x << 6;
  __shared__ short As[64][136];
  __shared__ union PB {
    short B[128][136];
    u8 ob[64][272];
  } pb;
  __shared__ float us[256];
  us[t] = uvec[t];
  {
    const uint4* src = (const uint4*)Vp;
    #pragma unroll
    for (int s = 0; s < 8; ++s) {
      int f = s * 256 + t;
      *(uint4*)&pb.B[f >> 4][(f & 15) * 8] = src[f];
    }
  }
  #pragma unroll
  for (int s = 0; s < 8; ++s) {
    int f = s * 256 + t;
    int row = f >> 5, q = f & 31;
    int gr = row0 + row; if (gr > 100000) gr = 100000;
    float4 v = *(const float4*)&emb[(size_t)gr * 128 + (q << 2)];
    ushort4 pk;
    pk.x = f2b(v.x); pk.y = f2b(v.y); pk.z = f2b(v.z); pk.w = f2b(v.w);
    *(ushort4*)&As[row][q << 2] = pk;
  }
  __syncthreads();
  {
    const int row = t >> 2, l = t & 3;
    int gr = row0 + row; if (gr > 100000) gr = 100000;
    const short* ar = &As[row][l * 32];
    const float* u0 = &us[l * 32];
    const float* u1 = &us[128 + l * 32];
    float p0 = 0.f, p1 = 0.f;
    #pragma unroll
    for (int i = 0; i < 32; ++i) {
      float e = __uint_as_float(((u32)(unsigned short)ar[i]) << 16);
      p0 += e * u0[i];
      p1 += e * u1[i];
    }
    p0 += __shfl_xor(p0, 1, 64); p0 += __shfl_xor(p0, 2, 64);
    p1 += __shfl_xor(p1, 1, 64); p1 += __shfl_xor(p1, 2, 64);
    if (l == 0) { srel[gr] = p0; sent[gr] = p1; }
  }
  const int wave = t >> 6, lane = t & 63;
  const int quad = lane >> 4, l16 = lane & 15;
  const int wm = (wave >> 1) << 5, wn = (wave & 1) << 6;
  f32x4 acc0[2][4], acc1[2][4];
  #pragma unroll
  for (int i = 0; i < 2; ++i)
    #pragma unroll
    for (int j = 0; j < 4; ++j) {
      acc0[i][j] = (f32x4){0.f, 0.f, 0.f, 0.f};
      acc1[i][j] = (f32x4){0.f, 0.f, 0.f, 0.f};
    }
  #pragma unroll
  for (int kc = 0; kc < 4; ++kc) {
    bf16x8 af[2], bfr[4];
    #pragma unroll
    for (int i = 0; i < 2; ++i)
      af[i] = *(const bf16x8*)&As[wm + i * 16 + l16][kc * 32 + quad * 8];
    #pragma unroll
    for (int j = 0; j < 4; ++j)
      bfr[j] = *(const bf16x8*)&pb.B[wn + j * 16 + l16][kc * 32 + quad * 8];
    #pragma unroll
    for (int i = 0; i < 2; ++i)
      #pragma unroll
      for (int j = 0; j < 4; ++j)
        acc0[i][j] = __builtin_amdgcn_mfma_f32_16x16x32_bf16(af[i], bfr[j], acc0[i][j], 0, 0, 0);
  }
  __syncthreads();
  {
    const uint4* src = (const uint4*)(Vp + 128 * 128);
    #pragma unroll
    for (int s = 0; s < 8; ++s) {
      int f = s * 256 + t;
      *(uint4*)&pb.B[f >> 4][(f & 15) * 8] = src[f];
    }
  }
  __syncthreads();
  #pragma unroll
  for (int kc = 0; kc < 4; ++kc) {
    bf16x8 af[2], bfr[4];
    #pragma unroll
    for (int i = 0; i < 2; ++i)
      af[i] = *(const bf16x8*)&As[wm + i * 16 + l16][kc * 32 + quad * 8];
    #pragma unroll
    for (int j = 0; j < 4; ++j)
      bfr[j] = *(const bf16x8*)&pb.B[wn + j * 16 + l16][kc * 32 + quad * 8];
    #pragma unroll
    for (int i = 0; i < 2; ++i)
      #pragma unroll
      for (int j = 0; j < 4; ++j)
        acc1[i][j] = __builtin_amdgcn_mfma_f32_16x16x32_bf16(af[i], bfr[j], acc1[i][j], 0, 0, 0);
  }
  __syncthreads();
  #pragma unroll
  for (int j = 0; j < 4; ++j) {
    const int col = wn + j * 16 + l16;
    #pragma unroll
    for (int i = 0; i < 2; ++i) {
      #pragma unroll
      for (int r = 0; r < 4; ++r) {
        int row = wm + i * 16 + quad * 4 + r;
        pb.ob[row][col] = enc8(acc0[i][j][r]);
        pb.ob[row][128 + col] = enc8(acc1[i][j][r]);
      }
    }
  }
  __syncthreads();
  #pragma unroll
  for (int s = 0; s < 4; ++s) {
    int c = s * 256 + t;
    int row = c >> 4, part = c & 15;
    int gr = row0 + row;
    if (gr <= 100000) {
      uint4 v = *(const uint4*)&pb.ob[row][part * 16];
      if (part < 8) *(uint4*)&pr[(size_t)gr * 128 + part * 16] = v;
      else          *(uint4*)&pe[(size_t)gr * 128 + (part - 8) * 16] = v;
    }
  }
}

// ---------------------------------------------------------------------------
// Merged neighbor encoder with uint8 tables.
__global__ __launch_bounds__(256) void k_neighbor(
    const int* __restrict__ q_l1, const int* __restrict__ q_l2,
    const int* __restrict__ q_r1, const int* __restrict__ q_r2,
    const int* __restrict__ s_l1, const int* __restrict__ s_l2,
    const int* __restrict__ s_r1, const int* __restrict__ s_r2,
    const u8* __restrict__ pr, const u8* __restrict__ pe,
    const float* __restrict__ srel, const float* __restrict__ sent,
    const float* __restrict__ gcn_wb, const float* __restrict__ gcn_b,
    const float* __restrict__ hop_gate,
    float* __restrict__ qn, float* __restrict__ sn, bf16u* __restrict__ XX)
{
  const int b = blockIdx.x, t = threadIdx.x;
  const int *cA, *cB; float* outp; bf16u* xxp; int n, coloff;
  if (b < 4096)      { cA = q_l1; cB = q_l2; n = b;        outp = qn; xxp = XX; coloff = 0; }
  else if (b < 8192) { cA = q_r1; cB = q_r2; n = b - 4096; outp = qn; xxp = XX; coloff = 128; }
  else if (b < 8197) { cA = s_l1; cB = s_l2; n = b - 8192; outp = sn; xxp = 0;  coloff = 0; }
  else               { cA = s_r1; cB = s_r2; n = b - 8197; outp = sn; xxp = 0;  coloff = 128; }
  __shared__ int idxA[64][2], idxB[64][2];
  __shared__ float wA[64], wB[64];
  __shared__ float red[2][8][16][8];
  if (t < 128) {
    const int hop = t >> 6, nn = t & 63;
    const int* conn = hop ? cB : cA;
    int rel = conn[(n * 64 + nn) * 2 + 0];
    int ent = conn[(n * 64 + nn) * 2 + 1];
    int (*idx)[2] = hop ? idxB : idxA;
    idx[nn][0] = rel; idx[nn][1] = ent;
    float sc = srel[rel] + sent[ent];
    float m = sc;
    #pragma unroll
    for (int off = 32; off; off >>= 1) m = fmaxf(m, __shfl_xor(m, off, 64));
    float e = __expf(sc - m);
    float s = e;
    #pragma unroll
    for (int off = 32; off; off >>= 1) s += __shfl_xor(s, off, 64);
    (hop ? wB : wA)[nn] = e / s;
  }
  __syncthreads();
  {
    const int hop = t >> 7, g = (t >> 4) & 7, p = t & 15;
    const int (*idx)[2] = hop ? idxB : idxA;
    const float* w = hop ? wB : wA;
    uint2 ra[8], rb[8];
    #pragma unroll
    for (int kk = 0; kk < 8; ++kk) {
      int k = g + (kk << 3);
      ra[kk] = *(const uint2*)&pr[(size_t)idx[k][0] * 128 + p * 8];
      rb[kk] = *(const uint2*)&pe[(size_t)idx[k][1] * 128 + p * 8];
    }
    float a[8];
    #pragma unroll
    for (int c = 0; c < 8; ++c) a[c] = 0.f;
    #pragma unroll
    for (int kk = 0; kk < 8; ++kk) {
      float wk = w[g + (kk << 3)];
      a[0] += wk * (ub0(ra[kk].x) + ub0(rb[kk].x));
      a[1] += wk * (ub1(ra[kk].x) + ub1(rb[kk].x));
      a[2] += wk * (ub2(ra[kk].x) + ub2(rb[kk].x));
      a[3] += wk * (ub3(ra[kk].x) + ub3(rb[kk].x));
      a[4] += wk * (ub0(ra[kk].y) + ub0(rb[kk].y));
      a[5] += wk * (ub1(ra[kk].y) + ub1(rb[kk].y));
      a[6] += wk * (ub2(ra[kk].y) + ub2(rb[kk].y));
      a[7] += wk * (ub3(ra[kk].y) + ub3(rb[kk].y));
    }
    *(float4*)&red[hop][g][p][0] = (float4){a[0], a[1], a[2], a[3]};
    *(float4*)&red[hop][g][p][4] = (float4){a[4], a[5], a[6], a[7]};
  }
  __syncthreads();
  if (t < 128) {
    const int d = t, p = d >> 3, cq = d & 7;
    float sA = 0.f, sB = 0.f;
    #pragma unroll
    for (int g = 0; g < 8; ++g) {
      sA += red[0][g][p][cq];
      sB += red[1][g][p][cq];
    }
    float accA = sA * (1.f / 512.f) - 0.5f;
    float accB = sB * (1.f / 512.f) - 0.5f;
    float bias = gcn_wb[d] + gcn_b[d];
    float g0 = hop_gate[0], g1 = hop_gate[1];
    float mx = fmaxf(g0, g1);
    float e0 = __expf(g0 - mx), e1 = __expf(g1 - mx);
    float inv = 1.f / (e0 + e1);
    float v = e0 * inv * tanhf(bias + accA) + e1 * inv * tanhf(bias + accB);
    outp[n * 256 + coloff + d] = v;
    if (xxp) xxp[(size_t)n * 576 + coloff + d] = f2b(v);
  }
}

// ---------------------------------------------------------------------------
__global__ __launch_bounds__(256) void k_sup1(
    const float* __restrict__ sn, const float* __restrict__ p1_w,
    const float* __restrict__ p1_b, float* __restrict__ h1)
{
  const int r = blockIdx.x >> 3, j0 = (blockIdx.x & 7) << 6;
  const int t = threadIdx.x;
  __shared__ float xs[256];
  xs[t] = sn[r * 256 + t];
  __syncthreads();
  const int j = j0 + (t >> 2), q = t & 3;
  const float* wr = p1_w + (size_t)j * 256 + q * 64;
  float acc = 0.f;
  #pragma unroll
  for (int k = 0; k < 64; ++k) acc += xs[q * 64 + k] * wr[k];
  acc += __shfl_xor(acc, 1, 64);
  acc += __shfl_xor(acc, 2, 64);
  if (q == 0) h1[r * 512 + j] = fmaxf(acc + p1_b[j], 0.f);
}

__global__ __launch_bounds__(256) void k_sup2(
    const float* __restrict__ sn, const float* __restrict__ h1,
    const float* __restrict__ p2_w, const float* __restrict__ p2_b,
    const float* __restrict__ ln_g, const float* __restrict__ ln_b,
    float* __restrict__ sg)
{
  const int r = blockIdx.x, t = threadIdx.x;
  const int lane = t & 63, wave = t >> 6;
  __shared__ float hs[512];
  __shared__ float zs[256];
  __shared__ float r1[4], r2[4];
  hs[t] = h1[r * 512 + t];
  hs[t + 256] = h1[r * 512 + 256 + t];
  __syncthreads();
  const int q = t & 3;
  #pragma unroll
  for (int jc = 0; jc < 4; ++jc) {
    int j = jc * 64 + (t >> 2);
    const float* wr = p2_w + (size_t)j * 512 + q * 128;
    float acc = 0.f;
    #pragma unroll
    for (int k = 0; k < 128; ++k) acc += hs[q * 128 + k] * wr[k];
    acc += __shfl_xor(acc, 1, 64);
    acc += __shfl_xor(acc, 2, 64);
    if (q == 0) zs[j] = acc + p2_b[j] + sn[r * 256 + j];
  }
  __syncthreads();
  float v = zs[t];
  float s1 = v, s2 = v * v;
  #pragma unroll
  for (int off = 32; off; off >>= 1) { s1 += __shfl_xor(s1, off, 64); s2 += __shfl_xor(s2, off, 64); }
  if (lane == 0) { r1[wave] = s1; r2[wave] = s2; }
  __syncthreads();
  float S1 = r1[0] + r1[1] + r1[2] + r1[3];
  float S2 = r2[0] + r2[1] + r2[2] + r2[3];
  float mu = S1 * (1.f / 256.f);
  float var = S2 * (1.f / 256.f) - mu * mu;
  sg[r * 256 + t] = (v - mu) * rsqrtf(var + 1e-6f) * ln_g[t] + ln_b[t];
}

// ---------------------------------------------------------------------------
__global__ __launch_bounds__(256) void k_sg2(
    const float* __restrict__ sg, const float* __restrict__ w_hh,
    bf16u* __restrict__ WWb, float* __restrict__ sm)
{
  __shared__ float s[5][256];
  const int t = threadIdx.x;
  for (int i = t; i < 1280; i += 256) s[i >> 8][i & 255] = sg[i];
  __syncthreads();
  if (blockIdx.x == 0)
    sm[t] = (s[0][t] + s[1][t] + s[2][t] + s[3][t] + s[4][t]) * 0.2f;
  const int j = (blockIdx.x << 6) + (t >> 2), q = t & 3;
  const float4* wr = (const float4*)(w_hh + (size_t)j * 512 + 256 + q * 64);
  float a[5] = {0.f, 0.f, 0.f, 0.f, 0.f};
  #pragma unroll
  for (int kk = 0; kk < 16; ++kk) {
    float4 w = wr[kk];
    int k = q * 64 + kk * 4;
    #pragma unroll
    for (int r = 0; r < 5; ++r)
      a[r] += s[r][k] * w.x + s[r][k+1] * w.y + s[r][k+2] * w.z + s[r][k+3] * w.w;
  }
  #pragma unroll
  for (int r = 0; r < 5; ++r) {
    a[r] += __shfl_xor(a[r], 1, 64);
    a[r] += __shfl_xor(a[r], 2, 64);
  }
  if (q == 0) {
    #pragma unroll
    for (int r = 0; r < 5; ++r)
      WWb[(size_t)j * 576 + 512 + r] = f2b(a[r]);
  }
}

// ---------------------------------------------------------------------------
// out[4096][2048] (bf16) = X @ W.T + (add tile | bsum), MFMA 16x16x32.
// r13 structure: 128x128 tile, grid 512, 32-wide K chunks, register
// prefetch, scatter epilogue, XCD swizzle. X/W pointers may be K-offset
// (stride 576 fixed).
__global__ __launch_bounds__(256) void k_gates_mfma(
    const bf16u* __restrict__ X, const bf16u* __restrict__ W,
    const float* __restrict__ bsum, const bf16u* __restrict__ add,
    bf16u* __restrict__ out, int kchunks)
{
  const int t = threadIdx.x;
  const int wave = t >> 6, lane = t & 63;
  const int quad = lane >> 4, l16 = lane & 15;
  const int wm = (wave >> 1) << 6, wn = (wave & 1) << 6;
  const int lin = (blockIdx.x & 7) * 64 + (blockIdx.x >> 3);
  const int row0 = (lin >> 4) << 7;
  const int col0 = (lin & 15) << 7;
  __shared__ short As[128][40];
  __shared__ short Bs[128][40];
  f32x4 acc[4][4];
  #pragma unroll
  for (int i = 0; i < 4; ++i)
    #pragma unroll
    for (int j = 0; j < 4; ++j) acc[i][j] = (f32x4){0.f, 0.f, 0.f, 0.f};

  const int srow = t >> 1, shalf = t & 1;
  const bf16u* xp = X + (size_t)(row0 + srow) * 576 + shalf * 16;
  const bf16u* wp = W + (size_t)(col0 + srow) * 576 + shalf * 16;

  uint4 x0 = *(const uint4*)(xp);
  uint4 x1 = *(const uint4*)(xp + 8);
  uint4 w0 = *(const uint4*)(wp);
  uint4 w1 = *(const uint4*)(wp + 8);

  for (int kc = 0; kc < kchunks; ++kc) {
    __syncthreads();
    *(uint4*)&As[srow][shalf * 16] = x0;
    *(uint4*)&As[srow][shalf * 16 + 8] = x1;
    *(uint4*)&Bs[srow][shalf * 16] = w0;
    *(uint4*)&Bs[srow][shalf * 16 + 8] = w1;
    __syncthreads();
    if (kc + 1 < kchunks) {
      x0 = *(const uint4*)(xp + (kc+1) * 32);
      x1 = *(const uint4*)(xp + (kc+1) * 32 + 8);
      w0 = *(const uint4*)(wp + (kc+1) * 32);
      w1 = *(const uint4*)(wp + (kc+1) * 32 + 8);
    }
    bf16x8 af[4], bfr[4];
    #pragma unroll
    for (int i = 0; i < 4; ++i)
      af[i] = *(const bf16x8*)&As[wm + i * 16 + l16][quad * 8];
    #pragma unroll
    for (int j = 0; j < 4; ++j)
      bfr[j] = *(const bf16x8*)&Bs[wn + j * 16 + l16][quad * 8];
    #pragma unroll
    for (int i = 0; i < 4; ++i)
      #pragma unroll
      for (int j = 0; j < 4; ++j)
        acc[i][j] = __builtin_amdgcn_mfma_f32_16x16x32_bf16(af[i], bfr[j], acc[i][j], 0, 0, 0);
  }

  #pragma unroll
  for (int j = 0; j < 4; ++j) {
    const int col = col0 + wn + j * 16 + l16;
    const float bs = add ? 0.f : bsum[col];
    #pragma unroll
    for (int i = 0; i < 4; ++i) {
      #pragma unroll
      for (int r = 0; r < 4; ++r) {
        int row = row0 + wm + i * 16 + quad * 4 + r;
        float base = add ? b2f(add[(size_t)row * 2048 + col]) : bs;
        out[(size_t)row * 2048 + col] = f2b(acc[i][j][r] + base);
      }
    }
  }
}

// ---------------------------------------------------------------------------
// Cell pointwise + attention (fused 5-way reduction, 1 barrier).
// Writes h (= qn + hc) into XX[b][256..512], attn into XX[b][512..517].
__global__ __launch_bounds__(256) void k_cell(
    const bf16u* __restrict__ gates, const float* __restrict__ qn,
    float* __restrict__ c, bf16u* __restrict__ XX,
    const float* __restrict__ sg, const float* __restrict__ sm,
    float* __restrict__ out, int step)
{
  __shared__ float red[4][6];
  const int b = blockIdx.x, t = threadIdx.x;
  const int lane = t & 63, wave = t >> 6;
  const bf16u* g = gates + (size_t)b * 2048;
  float i0 = b2f(g[t]),       f0 = b2f(g[512 + t]), gg0 = b2f(g[1024 + t]), o0 = b2f(g[1536 + t]);
  float i1 = b2f(g[256 + t]), f1 = b2f(g[768 + t]), gg1 = b2f(g[1280 + t]);
  float co0 = step ? c[b * 512 + t] : 0.f;
  float co1 = step ? c[b * 512 + 256 + t] : 0.f;
  float c0 = sigmoidf_(f0) * co0 + sigmoidf_(i0) * tanhf(gg0);
  float c1 = sigmoidf_(f1) * co1 + sigmoidf_(i1) * tanhf(gg1);
  c[b * 512 + t] = c0;
  c[b * 512 + 256 + t] = c1;
  float hcv = sigmoidf_(o0) * tanhf(c0);
  float h = qn[b * 256 + t] + hcv;
  if (step < 3) {
    XX[(size_t)b * 576 + 256 + t] = f2b(h);
    float dots[5];
    #pragma unroll
    for (int s = 0; s < 5; ++s) dots[s] = h * sg[s * 256 + t];
    #pragma unroll
    for (int off = 32; off; off >>= 1) {
      #pragma unroll
      for (int s = 0; s < 5; ++s) dots[s] += __shfl_xor(dots[s], off, 64);
    }
    if (lane == 0) {
      #pragma unroll
      for (int s = 0; s < 5; ++s) red[wave][s] = dots[s];
    }
    __syncthreads();
    #pragma unroll
    for (int s = 0; s < 5; ++s)
      dots[s] = red[0][s] + red[1][s] + red[2][s] + red[3][s];
    float m = dots[0];
    #pragma unroll
    for (int s = 1; s < 5; ++s) m = fmaxf(m, dots[s]);
    float sum = 0.f;
    #pragma unroll
    for (int s = 0; s < 5; ++s) sum += __expf(dots[s] - m);
    if (t < 5) {
      float dv = (t == 1) ? dots[1] : (t == 2) ? dots[2] : (t == 3) ? dots[3]
               : (t == 4) ? dots[4] : dots[0];
      XX[(size_t)b * 576 + 512 + t] = f2b(__expf(dv - m) / sum);
    }
  } else {
    float v = h * sm[t];
    #pragma unroll
    for (int off = 32; off; off >>= 1) v += __shfl_xor(v, off, 64);
    if (lane == 0) red[wave][0] = v;
    __syncthreads();
    if (t == 0) out[b] = red[0][0] + red[1][0] + red[2][0] + red[3][0];
  }
}

// ---------------------------------------------------------------------------
extern "C" void kernel_launch(void* const* d_in, const int* in_sizes, int n_in,
                              void* d_out, int out_size, void* d_ws, size_t ws_size,
                              hipStream_t stream)
{
  (void)in_sizes; (void)n_in; (void)out_size; (void)ws_size;
  const int *q_l1 = (const int*)d_in[0], *q_l2 = (const int*)d_in[1];
  const int *q_r1 = (const int*)d_in[2], *q_r2 = (const int*)d_in[3];
  const int *s_l1 = (const int*)d_in[4], *s_l2 = (const int*)d_in[5];
  const int *s_r1 = (const int*)d_in[6], *s_r2 = (const int*)d_in[7];
  const float* emb      = (const float*)d_in[12];
  const float* gcn_w    = (const float*)d_in[13];
  const float* gcn_wb   = (const float*)d_in[14];
  const float* gcn_b    = (const float*)d_in[15];
  const float* hop_gate = (const float*)d_in[16];
  const float* attn_w   = (const float*)d_in[17];
  const float* p1_w = (const float*)d_in[19];
  const float* p1_b = (const float*)d_in[20];
  const float* p2_w = (const float*)d_in[21];
  const float* p2_b = (const float*)d_in[22];
  const float* ln_g = (const float*)d_in[23];
  const float* ln_b = (const float*)d_in[24];
  const float* w_ih = (const float*)d_in[25];
  const float* w_hh = (const float*)d_in[26];
  const float* b_ih = (const float*)d_in[27];
  const float* b_hh = (const float*)d_in[28];

  char* base = (char*)d_ws;
  size_t off = 0;
  auto alloc = [&](size_t bytes) -> char* {
    char* r = base + off;
    off = (off + bytes + 255) & ~(size_t)255;
    return r;
  };
  u8* pr       = (u8*)alloc(100001ull * 128);
  u8* pe       = (u8*)alloc(100001ull * 128);
  float* srel  = (float*)alloc(100001ull * 4);
  float* sent  = (float*)alloc(100001ull * 4);
  float* uvec  = (float*)alloc(256 * 4);
  bf16u* Vp    = (bf16u*)alloc(256 * 128 * 2);
  float* qn    = (float*)alloc(4096ull * 256 * 4);
  float* sn    = (float*)alloc(5 * 256 * 4);
  float* sg    = (float*)alloc(5 * 256 * 4);
  float* sm    = (float*)alloc(256 * 4);
  float* h1b   = (float*)alloc(5 * 512 * 4);
  bf16u* XX    = (bf16u*)alloc(4096ull * 576 * 2);
  bf16u* WWa   = (bf16u*)alloc(2048ull * 576 * 2);
  bf16u* WWb   = (bf16u*)alloc(2048ull * 576 * 2);
  float* bsum  = (float*)alloc(2048 * 4);
  bf16u* gates0 = (bf16u*)alloc(4096ull * 2048 * 2);
  bf16u* gates  = (bf16u*)alloc(4096ull * 2048 * 2);
  float* cbuf  = (float*)alloc(4096ull * 512 * 4);

  k_prep<<<4096, 256, 0, stream>>>(gcn_w, attn_w, w_ih, w_hh, b_ih, b_hh,
                                   Vp, uvec, WWa, WWb, bsum, XX);
  k_pre_gemm<<<1563, 256, 0, stream>>>(emb, Vp, uvec, pr, pe, srel, sent);
  k_neighbor<<<8202, 256, 0, stream>>>(q_l1, q_l2, q_r1, q_r2, s_l1, s_l2, s_r1, s_r2,
                                       pr, pe, srel, sent, gcn_wb, gcn_b, hop_gate,
                                       qn, sn, XX);
  k_sup1<<<40, 256, 0, stream>>>(sn, p1_w, p1_b, h1b);
  k_sup2<<<5, 256, 0, stream>>>(sn, h1b, p2_w, p2_b, ln_g, ln_b, sg);
  k_sg2<<<32, 256, 0, stream>>>(sg, w_hh, WWb, sm);

  // step 0: gates0 = qn@w_ih.T + bsum  (K=256, 8 chunks)
  k_gates_mfma<<<512, 256, 0, stream>>>(XX, WWa, bsum, (const bf16u*)nullptr, gates0, 8);
  k_cell<<<4096, 256, 0, stream>>>(gates0, qn, cbuf, XX, sg, sm, (float*)d_out, 0);
  // steps 1-3: gates = [h|attn|0] @ [Whh1|SG2|0].T + gates0  (K=288, 9 chunks)
  for (int step = 1; step < 4; ++step) {
    k_gates_mfma<<<512, 256, 0, stream>>>(XX + 256, WWb + 256, bsum, gates0, gates, 9);
    k_cell<<<4096, 256, 0, stream>>>(gates, qn, cbuf, XX, sg, sm, (float*)d_out, step);
  }
}

// Round 17
// 336.439 us; speedup vs baseline: 1.0922x; 1.0922x over previous
//
#include <hip/hip_runtime.h>

typedef unsigned short bf16u;
typedef unsigned char u8;
typedef unsigned int u32;
typedef float f32x4 __attribute__((ext_vector_type(4)));
typedef short bf16x8 __attribute__((ext_vector_type(8)));

__device__ inline float sigmoidf_(float x) { return 1.f / (1.f + __expf(-x)); }
__device__ inline float b2f(bf16u u) { return __uint_as_float(((u32)u) << 16); }
__device__ inline bf16u f2b(float f) {
  u32 i = __float_as_uint(f);
  u32 r = (i + 0x7fffu + ((i >> 16) & 1u)) >> 16;
  return (bf16u)r;
}
// uint8 table codec: stored = clamp(round(v*512 + 128)); decoded = u/512 - 0.25
__device__ inline u8 enc8(float v) {
  float q = fmaf(v, 512.f, 128.5f);
  q = fminf(fmaxf(q, 0.f), 255.f);
  return (u8)(int)q;
}
__device__ inline float ub0(u32 u) { return (float)(u & 0xffu); }
__device__ inline float ub1(u32 u) { return (float)((u >> 8) & 0xffu); }
__device__ inline float ub2(u32 u) { return (float)((u >> 16) & 0xffu); }
__device__ inline float ub3(u32 u) { return (float)(u >> 24); }

// ---------------------------------------------------------------------------
// Fused prep: XX pad zero (all 4096 blocks), LSTM weight pack (b<2048),
// Vp bf16 conversion (b in [2048,2304)), uvec (b==2304).
__global__ __launch_bounds__(256) void k_prep(
    const float* __restrict__ gcn_w, const float* __restrict__ attn_w,
    const float* __restrict__ w_ih, const float* __restrict__ w_hh,
    const float* __restrict__ b_ih, const float* __restrict__ b_hh,
    bf16u* __restrict__ Vp, float* __restrict__ uvec,
    bf16u* __restrict__ WWa, bf16u* __restrict__ WWb, float* __restrict__ bsum,
    bf16u* __restrict__ XX)
{
  const int b = blockIdx.x, t = threadIdx.x;
  if (t < 59) XX[(size_t)b * 576 + 517 + t] = 0;
  if (b < 2048) {
    float wi = w_ih[b * 256 + t];
    float wh = w_hh[b * 512 + t];
    WWa[(size_t)b * 576 + t] = f2b(wi);
    WWb[(size_t)b * 576 + t] = f2b(wi + wh);
    WWb[(size_t)b * 576 + 256 + t] = f2b(wh);
    if (t < 59) WWb[(size_t)b * 576 + 517 + t] = 0;
    if (t == 0) bsum[b] = b_ih[b] + b_hh[b];
  } else if (b < 2304) {
    const int o = b - 2048;
    if (t < 128) Vp[o * 128 + t] = f2b(gcn_w[(o & 127) * 256 + ((o >> 7) << 7) + t]);
  } else if (b == 2304) {
    const int col = ((t >> 7) << 7) + (t & 127);
    float acc = 0.f;
    for (int d = 0; d < 128; ++d) acc += gcn_w[d * 256 + col] * attn_w[d];
    uvec[t] = acc;
  }
}

// ---------------------------------------------------------------------------
// pr/pe tables (uint8) via bf16 MFMA; scores post-staging from LDS.
__global__ __launch_bounds__(256) void k_pre_gemm(
    const float* __restrict__ emb, const bf16u* __restrict__ Vp,
    const float* __restrict__ uvec,
    u8* __restrict__ pr, u8* __restrict__ pe,
    float* __restrict__ srel, float* __restrict__ sent)
{
  const int t = threadIdx.x;
  const int row0 = blockIdx.x << 6;
  __shared__ short As[64][136];
  __shared__ union PB {
    short B[128][136];
    u8 ob[64][272];
  } pb;
  __shared__ float us[256];
  us[t] = uvec[t];
  {
    const uint4* src = (const uint4*)Vp;
    #pragma unroll
    for (int s = 0; s < 8; ++s) {
      int f = s * 256 + t;
      *(uint4*)&pb.B[f >> 4][(f & 15) * 8] = src[f];
    }
  }
  #pragma unroll
  for (int s = 0; s < 8; ++s) {
    int f = s * 256 + t;
    int row = f >> 5, q = f & 31;
    int gr = row0 + row; if (gr > 100000) gr = 100000;
    float4 v = *(const float4*)&emb[(size_t)gr * 128 + (q << 2)];
    ushort4 pk;
    pk.x = f2b(v.x); pk.y = f2b(v.y); pk.z = f2b(v.z); pk.w = f2b(v.w);
    *(ushort4*)&As[row][q << 2] = pk;
  }
  __syncthreads();
  {
    const int row = t >> 2, l = t & 3;
    int gr = row0 + row; if (gr > 100000) gr = 100000;
    const short* ar = &As[row][l * 32];
    const float* u0 = &us[l * 32];
    const float* u1 = &us[128 + l * 32];
    float p0 = 0.f, p1 = 0.f;
    #pragma unroll
    for (int i = 0; i < 32; ++i) {
      float e = __uint_as_float(((u32)(unsigned short)ar[i]) << 16);
      p0 += e * u0[i];
      p1 += e * u1[i];
    }
    p0 += __shfl_xor(p0, 1, 64); p0 += __shfl_xor(p0, 2, 64);
    p1 += __shfl_xor(p1, 1, 64); p1 += __shfl_xor(p1, 2, 64);
    if (l == 0) { srel[gr] = p0; sent[gr] = p1; }
  }
  const int wave = t >> 6, lane = t & 63;
  const int quad = lane >> 4, l16 = lane & 15;
  const int wm = (wave >> 1) << 5, wn = (wave & 1) << 6;
  f32x4 acc0[2][4], acc1[2][4];
  #pragma unroll
  for (int i = 0; i < 2; ++i)
    #pragma unroll
    for (int j = 0; j < 4; ++j) {
      acc0[i][j] = (f32x4){0.f, 0.f, 0.f, 0.f};
      acc1[i][j] = (f32x4){0.f, 0.f, 0.f, 0.f};
    }
  #pragma unroll
  for (int kc = 0; kc < 4; ++kc) {
    bf16x8 af[2], bfr[4];
    #pragma unroll
    for (int i = 0; i < 2; ++i)
      af[i] = *(const bf16x8*)&As[wm + i * 16 + l16][kc * 32 + quad * 8];
    #pragma unroll
    for (int j = 0; j < 4; ++j)
      bfr[j] = *(const bf16x8*)&pb.B[wn + j * 16 + l16][kc * 32 + quad * 8];
    #pragma unroll
    for (int i = 0; i < 2; ++i)
      #pragma unroll
      for (int j = 0; j < 4; ++j)
        acc0[i][j] = __builtin_amdgcn_mfma_f32_16x16x32_bf16(af[i], bfr[j], acc0[i][j], 0, 0, 0);
  }
  __syncthreads();
  {
    const uint4* src = (const uint4*)(Vp + 128 * 128);
    #pragma unroll
    for (int s = 0; s < 8; ++s) {
      int f = s * 256 + t;
      *(uint4*)&pb.B[f >> 4][(f & 15) * 8] = src[f];
    }
  }
  __syncthreads();
  #pragma unroll
  for (int kc = 0; kc < 4; ++kc) {
    bf16x8 af[2], bfr[4];
    #pragma unroll
    for (int i = 0; i < 2; ++i)
      af[i] = *(const bf16x8*)&As[wm + i * 16 + l16][kc * 32 + quad * 8];
    #pragma unroll
    for (int j = 0; j < 4; ++j)
      bfr[j] = *(const bf16x8*)&pb.B[wn + j * 16 + l16][kc * 32 + quad * 8];
    #pragma unroll
    for (int i = 0; i < 2; ++i)
      #pragma unroll
      for (int j = 0; j < 4; ++j)
        acc1[i][j] = __builtin_amdgcn_mfma_f32_16x16x32_bf16(af[i], bfr[j], acc1[i][j], 0, 0, 0);
  }
  __syncthreads();
  #pragma unroll
  for (int j = 0; j < 4; ++j) {
    const int col = wn + j * 16 + l16;
    #pragma unroll
    for (int i = 0; i < 2; ++i) {
      #pragma unroll
      for (int r = 0; r < 4; ++r) {
        int row = wm + i * 16 + quad * 4 + r;
        pb.ob[row][col] = enc8(acc0[i][j][r]);
        pb.ob[row][128 + col] = enc8(acc1[i][j][r]);
      }
    }
  }
  __syncthreads();
  #pragma unroll
  for (int s = 0; s < 4; ++s) {
    int c = s * 256 + t;
    int row = c >> 4, part = c & 15;
    int gr = row0 + row;
    if (gr <= 100000) {
      uint4 v = *(const uint4*)&pb.ob[row][part * 16];
      if (part < 8) *(uint4*)&pr[(size_t)gr * 128 + part * 16] = v;
      else          *(uint4*)&pe[(size_t)gr * 128 + (part - 8) * 16] = v;
    }
  }
}

// ---------------------------------------------------------------------------
// Merged neighbor encoder with uint8 tables.
__global__ __launch_bounds__(256) void k_neighbor(
    const int* __restrict__ q_l1, const int* __restrict__ q_l2,
    const int* __restrict__ q_r1, const int* __restrict__ q_r2,
    const int* __restrict__ s_l1, const int* __restrict__ s_l2,
    const int* __restrict__ s_r1, const int* __restrict__ s_r2,
    const u8* __restrict__ pr, const u8* __restrict__ pe,
    const float* __restrict__ srel, const float* __restrict__ sent,
    const float* __restrict__ gcn_wb, const float* __restrict__ gcn_b,
    const float* __restrict__ hop_gate,
    float* __restrict__ qn, float* __restrict__ sn, bf16u* __restrict__ XX)
{
  const int b = blockIdx.x, t = threadIdx.x;
  const int *cA, *cB; float* outp; bf16u* xxp; int n, coloff;
  if (b < 4096)      { cA = q_l1; cB = q_l2; n = b;        outp = qn; xxp = XX; coloff = 0; }
  else if (b < 8192) { cA = q_r1; cB = q_r2; n = b - 4096; outp = qn; xxp = XX; coloff = 128; }
  else if (b < 8197) { cA = s_l1; cB = s_l2; n = b - 8192; outp = sn; xxp = 0;  coloff = 0; }
  else               { cA = s_r1; cB = s_r2; n = b - 8197; outp = sn; xxp = 0;  coloff = 128; }
  __shared__ int idxA[64][2], idxB[64][2];
  __shared__ float wA[64], wB[64];
  __shared__ float red[2][8][16][8];
  if (t < 128) {
    const int hop = t >> 6, nn = t & 63;
    const int* conn = hop ? cB : cA;
    int rel = conn[(n * 64 + nn) * 2 + 0];
    int ent = conn[(n * 64 + nn) * 2 + 1];
    int (*idx)[2] = hop ? idxB : idxA;
    idx[nn][0] = rel; idx[nn][1] = ent;
    float sc = srel[rel] + sent[ent];
    float m = sc;
    #pragma unroll
    for (int off = 32; off; off >>= 1) m = fmaxf(m, __shfl_xor(m, off, 64));
    float e = __expf(sc - m);
    float s = e;
    #pragma unroll
    for (int off = 32; off; off >>= 1) s += __shfl_xor(s, off, 64);
    (hop ? wB : wA)[nn] = e / s;
  }
  __syncthreads();
  {
    const int hop = t >> 7, g = (t >> 4) & 7, p = t & 15;
    const int (*idx)[2] = hop ? idxB : idxA;
    const float* w = hop ? wB : wA;
    uint2 ra[8], rb[8];
    #pragma unroll
    for (int kk = 0; kk < 8; ++kk) {
      int k = g + (kk << 3);
      ra[kk] = *(const uint2*)&pr[(size_t)idx[k][0] * 128 + p * 8];
      rb[kk] = *(const uint2*)&pe[(size_t)idx[k][1] * 128 + p * 8];
    }
    float a[8];
    #pragma unroll
    for (int c = 0; c < 8; ++c) a[c] = 0.f;
    #pragma unroll
    for (int kk = 0; kk < 8; ++kk) {
      float wk = w[g + (kk << 3)];
      a[0] += wk * (ub0(ra[kk].x) + ub0(rb[kk].x));
      a[1] += wk * (ub1(ra[kk].x) + ub1(rb[kk].x));
      a[2] += wk * (ub2(ra[kk].x) + ub2(rb[kk].x));
      a[3] += wk * (ub3(ra[kk].x) + ub3(rb[kk].x));
      a[4] += wk * (ub0(ra[kk].y) + ub0(rb[kk].y));
      a[5] += wk * (ub1(ra[kk].y) + ub1(rb[kk].y));
      a[6] += wk * (ub2(ra[kk].y) + ub2(rb[kk].y));
      a[7] += wk * (ub3(ra[kk].y) + ub3(rb[kk].y));
    }
    *(float4*)&red[hop][g][p][0] = (float4){a[0], a[1], a[2], a[3]};
    *(float4*)&red[hop][g][p][4] = (float4){a[4], a[5], a[6], a[7]};
  }
  __syncthreads();
  if (t < 128) {
    const int d = t, p = d >> 3, cq = d & 7;
    float sA = 0.f, sB = 0.f;
    #pragma unroll
    for (int g = 0; g < 8; ++g) {
      sA += red[0][g][p][cq];
      sB += red[1][g][p][cq];
    }
    float accA = sA * (1.f / 512.f) - 0.5f;
    float accB = sB * (1.f / 512.f) - 0.5f;
    float bias = gcn_wb[d] + gcn_b[d];
    float g0 = hop_gate[0], g1 = hop_gate[1];
    float mx = fmaxf(g0, g1);
    float e0 = __expf(g0 - mx), e1 = __expf(g1 - mx);
    float inv = 1.f / (e0 + e1);
    float v = e0 * inv * tanhf(bias + accA) + e1 * inv * tanhf(bias + accB);
    outp[n * 256 + coloff + d] = v;
    if (xxp) xxp[(size_t)n * 576 + coloff + d] = f2b(v);
  }
}

// ---------------------------------------------------------------------------
__global__ __launch_bounds__(256) void k_sup1(
    const float* __restrict__ sn, const float* __restrict__ p1_w,
    const float* __restrict__ p1_b, float* __restrict__ h1)
{
  const int r = blockIdx.x >> 3, j0 = (blockIdx.x & 7) << 6;
  const int t = threadIdx.x;
  __shared__ float xs[256];
  xs[t] = sn[r * 256 + t];
  __syncthreads();
  const int j = j0 + (t >> 2), q = t & 3;
  const float* wr = p1_w + (size_t)j * 256 + q * 64;
  float acc = 0.f;
  #pragma unroll
  for (int k = 0; k < 64; ++k) acc += xs[q * 64 + k] * wr[k];
  acc += __shfl_xor(acc, 1, 64);
  acc += __shfl_xor(acc, 2, 64);
  if (q == 0) h1[r * 512 + j] = fmaxf(acc + p1_b[j], 0.f);
}

__global__ __launch_bounds__(256) void k_sup2(
    const float* __restrict__ sn, const float* __restrict__ h1,
    const float* __restrict__ p2_w, const float* __restrict__ p2_b,
    const float* __restrict__ ln_g, const float* __restrict__ ln_b,
    float* __restrict__ sg)
{
  const int r = blockIdx.x, t = threadIdx.x;
  const int lane = t & 63, wave = t >> 6;
  __shared__ float hs[512];
  __shared__ float zs[256];
  __shared__ float r1[4], r2[4];
  hs[t] = h1[r * 512 + t];
  hs[t + 256] = h1[r * 512 + 256 + t];
  __syncthreads();
  const int q = t & 3;
  #pragma unroll
  for (int jc = 0; jc < 4; ++jc) {
    int j = jc * 64 + (t >> 2);
    const float* wr = p2_w + (size_t)j * 512 + q * 128;
    float acc = 0.f;
    #pragma unroll
    for (int k = 0; k < 128; ++k) acc += hs[q * 128 + k] * wr[k];
    acc += __shfl_xor(acc, 1, 64);
    acc += __shfl_xor(acc, 2, 64);
    if (q == 0) zs[j] = acc + p2_b[j] + sn[r * 256 + j];
  }
  __syncthreads();
  float v = zs[t];
  float s1 = v, s2 = v * v;
  #pragma unroll
  for (int off = 32; off; off >>= 1) { s1 += __shfl_xor(s1, off, 64); s2 += __shfl_xor(s2, off, 64); }
  if (lane == 0) { r1[wave] = s1; r2[wave] = s2; }
  __syncthreads();
  float S1 = r1[0] + r1[1] + r1[2] + r1[3];
  float S2 = r2[0] + r2[1] + r2[2] + r2[3];
  float mu = S1 * (1.f / 256.f);
  float var = S2 * (1.f / 256.f) - mu * mu;
  sg[r * 256 + t] = (v - mu) * rsqrtf(var + 1e-6f) * ln_g[t] + ln_b[t];
}

// ---------------------------------------------------------------------------
__global__ __launch_bounds__(256) void k_sg2(
    const float* __restrict__ sg, const float* __restrict__ w_hh,
    bf16u* __restrict__ WWb, float* __restrict__ sm)
{
  __shared__ float s[5][256];
  const int t = threadIdx.x;
  for (int i = t; i < 1280; i += 256) s[i >> 8][i & 255] = sg[i];
  __syncthreads();
  if (blockIdx.x == 0)
    sm[t] = (s[0][t] + s[1][t] + s[2][t] + s[3][t] + s[4][t]) * 0.2f;
  const int j = (blockIdx.x << 6) + (t >> 2), q = t & 3;
  const float4* wr = (const float4*)(w_hh + (size_t)j * 512 + 256 + q * 64);
  float a[5] = {0.f, 0.f, 0.f, 0.f, 0.f};
  #pragma unroll
  for (int kk = 0; kk < 16; ++kk) {
    float4 w = wr[kk];
    int k = q * 64 + kk * 4;
    #pragma unroll
    for (int r = 0; r < 5; ++r)
      a[r] += s[r][k] * w.x + s[r][k+1] * w.y + s[r][k+2] * w.z + s[r][k+3] * w.w;
  }
  #pragma unroll
  for (int r = 0; r < 5; ++r) {
    a[r] += __shfl_xor(a[r], 1, 64);
    a[r] += __shfl_xor(a[r], 2, 64);
  }
  if (q == 0) {
    #pragma unroll
    for (int r = 0; r < 5; ++r)
      WWb[(size_t)j * 576 + 512 + r] = f2b(a[r]);
  }
}

// ---------------------------------------------------------------------------
// gates[4096][2048-stride] (bf16) = XX @ WW.T + bsum, MFMA 16x16x32.
// r13 structure: 128x128 tile, 32-wide K chunks, register prefetch, scatter
// epilogue, XCD swizzle. Only cols 0..1791 computed (o-gate upper half is
// never read) -> 14 col panels, grid 448.
__global__ __launch_bounds__(256) void k_gates_mfma(
    const bf16u* __restrict__ XX, const bf16u* __restrict__ WW,
    const float* __restrict__ bsum, bf16u* __restrict__ gates, int kchunks)
{
  const int t = threadIdx.x;
  const int wave = t >> 6, lane = t & 63;
  const int quad = lane >> 4, l16 = lane & 15;
  const int wm = (wave >> 1) << 6, wn = (wave & 1) << 6;
  // XCD swizzle over 448 blocks: 32 row panels x 14 col panels
  const int lin = (blockIdx.x & 7) * 56 + (blockIdx.x >> 3);
  const int row0 = (lin / 14) << 7;
  const int col0 = (lin % 14) << 7;
  __shared__ short As[128][40];
  __shared__ short Bs[128][40];
  f32x4 acc[4][4];
  #pragma unroll
  for (int i = 0; i < 4; ++i)
    #pragma unroll
    for (int j = 0; j < 4; ++j) acc[i][j] = (f32x4){0.f, 0.f, 0.f, 0.f};

  const int srow = t >> 1, shalf = t & 1;
  const bf16u* xp = XX + (size_t)(row0 + srow) * 576 + shalf * 16;
  const bf16u* wp = WW + (size_t)(col0 + srow) * 576 + shalf * 16;

  uint4 x0 = *(const uint4*)(xp);
  uint4 x1 = *(const uint4*)(xp + 8);
  uint4 w0 = *(const uint4*)(wp);
  uint4 w1 = *(const uint4*)(wp + 8);

  for (int kc = 0; kc < kchunks; ++kc) {
    __syncthreads();
    *(uint4*)&As[srow][shalf * 16] = x0;
    *(uint4*)&As[srow][shalf * 16 + 8] = x1;
    *(uint4*)&Bs[srow][shalf * 16] = w0;
    *(uint4*)&Bs[srow][shalf * 16 + 8] = w1;
    __syncthreads();
    if (kc + 1 < kchunks) {
      x0 = *(const uint4*)(xp + (kc+1) * 32);
      x1 = *(const uint4*)(xp + (kc+1) * 32 + 8);
      w0 = *(const uint4*)(wp + (kc+1) * 32);
      w1 = *(const uint4*)(wp + (kc+1) * 32 + 8);
    }
    bf16x8 af[4], bfr[4];
    #pragma unroll
    for (int i = 0; i < 4; ++i)
      af[i] = *(const bf16x8*)&As[wm + i * 16 + l16][quad * 8];
    #pragma unroll
    for (int j = 0; j < 4; ++j)
      bfr[j] = *(const bf16x8*)&Bs[wn + j * 16 + l16][quad * 8];
    #pragma unroll
    for (int i = 0; i < 4; ++i)
      #pragma unroll
      for (int j = 0; j < 4; ++j)
        acc[i][j] = __builtin_amdgcn_mfma_f32_16x16x32_bf16(af[i], bfr[j], acc[i][j], 0, 0, 0);
  }

  #pragma unroll
  for (int j = 0; j < 4; ++j) {
    const int col = col0 + wn + j * 16 + l16;
    const float bs = bsum[col];
    #pragma unroll
    for (int i = 0; i < 4; ++i) {
      #pragma unroll
      for (int r = 0; r < 4; ++r) {
        int row = row0 + wm + i * 16 + quad * 4 + r;
        gates[(size_t)row * 2048 + col] = f2b(acc[i][j][r] + bs);
      }
    }
  }
}

// ---------------------------------------------------------------------------
// Cell pointwise + attention (fused 5-way reduction, 1 barrier).
__global__ __launch_bounds__(256) void k_cell(
    const bf16u* __restrict__ gates, const float* __restrict__ qn,
    float* __restrict__ c, bf16u* __restrict__ XX,
    const float* __restrict__ sg, const float* __restrict__ sm,
    float* __restrict__ out, int step)
{
  __shared__ float red[4][6];
  const int b = blockIdx.x, t = threadIdx.x;
  const int lane = t & 63, wave = t >> 6;
  const bf16u* g = gates + (size_t)b * 2048;
  float i0 = b2f(g[t]),       f0 = b2f(g[512 + t]), gg0 = b2f(g[1024 + t]), o0 = b2f(g[1536 + t]);
  float i1 = b2f(g[256 + t]), f1 = b2f(g[768 + t]), gg1 = b2f(g[1280 + t]);
  float co0 = step ? c[b * 512 + t] : 0.f;
  float co1 = step ? c[b * 512 + 256 + t] : 0.f;
  float c0 = sigmoidf_(f0) * co0 + sigmoidf_(i0) * tanhf(gg0);
  float c1 = sigmoidf_(f1) * co1 + sigmoidf_(i1) * tanhf(gg1);
  c[b * 512 + t] = c0;
  c[b * 512 + 256 + t] = c1;
  float hcv = sigmoidf_(o0) * tanhf(c0);
  float h = qn[b * 256 + t] + hcv;
  if (step < 3) {
    XX[(size_t)b * 576 + 256 + t] = f2b(hcv);
    float dots[5];
    #pragma unroll
    for (int s = 0; s < 5; ++s) dots[s] = h * sg[s * 256 + t];
    #pragma unroll
    for (int off = 32; off; off >>= 1) {
      #pragma unroll
      for (int s = 0; s < 5; ++s) dots[s] += __shfl_xor(dots[s], off, 64);
    }
    if (lane == 0) {
      #pragma unroll
      for (int s = 0; s < 5; ++s) red[wave][s] = dots[s];
    }
    __syncthreads();
    #pragma unroll
    for (int s = 0; s < 5; ++s)
      dots[s] = red[0][s] + red[1][s] + red[2][s] + red[3][s];
    float m = dots[0];
    #pragma unroll
    for (int s = 1; s < 5; ++s) m = fmaxf(m, dots[s]);
    float sum = 0.f;
    #pragma unroll
    for (int s = 0; s < 5; ++s) sum += __expf(dots[s] - m);
    if (t < 5) {
      float dv = (t == 1) ? dots[1] : (t == 2) ? dots[2] : (t == 3) ? dots[3]
               : (t == 4) ? dots[4] : dots[0];
      XX[(size_t)b * 576 + 512 + t] = f2b(__expf(dv - m) / sum);
    }
  } else {
    float v = h * sm[t];
    #pragma unroll
    for (int off = 32; off; off >>= 1) v += __shfl_xor(v, off, 64);
    if (lane == 0) red[wave][0] = v;
    __syncthreads();
    if (t == 0) out[b] = red[0][0] + red[1][0] + red[2][0] + red[3][0];
  }
}

// ---------------------------------------------------------------------------
extern "C" void kernel_launch(void* const* d_in, const int* in_sizes, int n_in,
                              void* d_out, int out_size, void* d_ws, size_t ws_size,
                              hipStream_t stream)
{
  (void)in_sizes; (void)n_in; (void)out_size; (void)ws_size;
  const int *q_l1 = (const int*)d_in[0], *q_l2 = (const int*)d_in[1];
  const int *q_r1 = (const int*)d_in[2], *q_r2 = (const int*)d_in[3];
  const int *s_l1 = (const int*)d_in[4], *s_l2 = (const int*)d_in[5];
  const int *s_r1 = (const int*)d_in[6], *s_r2 = (const int*)d_in[7];
  const float* emb      = (const float*)d_in[12];
  const float* gcn_w    = (const float*)d_in[13];
  const float* gcn_wb   = (const float*)d_in[14];
  const float* gcn_b    = (const float*)d_in[15];
  const float* hop_gate = (const float*)d_in[16];
  const float* attn_w   = (const float*)d_in[17];
  const float* p1_w = (const float*)d_in[19];
  const float* p1_b = (const float*)d_in[20];
  const float* p2_w = (const float*)d_in[21];
  const float* p2_b = (const float*)d_in[22];
  const float* ln_g = (const float*)d_in[23];
  const float* ln_b = (const float*)d_in[24];
  const float* w_ih = (const float*)d_in[25];
  const float* w_hh = (const float*)d_in[26];
  const float* b_ih = (const float*)d_in[27];
  const float* b_hh = (const float*)d_in[28];

  char* base = (char*)d_ws;
  size_t off = 0;
  auto alloc = [&](size_t bytes) -> char* {
    char* r = base + off;
    off = (off + bytes + 255) & ~(size_t)255;
    return r;
  };
  u8* pr       = (u8*)alloc(100001ull * 128);
  u8* pe       = (u8*)alloc(100001ull * 128);
  float* srel  = (float*)alloc(100001ull * 4);
  float* sent  = (float*)alloc(100001ull * 4);
  float* uvec  = (float*)alloc(256 * 4);
  bf16u* Vp    = (bf16u*)alloc(256 * 128 * 2);
  float* qn    = (float*)alloc(4096ull * 256 * 4);
  float* sn    = (float*)alloc(5 * 256 * 4);
  float* sg    = (float*)alloc(5 * 256 * 4);
  float* sm    = (float*)alloc(256 * 4);
  float* h1b   = (float*)alloc(5 * 512 * 4);
  bf16u* XX    = (bf16u*)alloc(4096ull * 576 * 2);
  bf16u* WWa   = (bf16u*)alloc(2048ull * 576 * 2);
  bf16u* WWb   = (bf16u*)alloc(2048ull * 576 * 2);
  float* bsum  = (float*)alloc(2048 * 4);
  bf16u* gates = (bf16u*)alloc(4096ull * 2048 * 2);
  float* cbuf  = (float*)alloc(4096ull * 512 * 4);

  k_prep<<<4096, 256, 0, stream>>>(gcn_w, attn_w, w_ih, w_hh, b_ih, b_hh,
                                   Vp, uvec, WWa, WWb, bsum, XX);
  k_pre_gemm<<<1563, 256, 0, stream>>>(emb, Vp, uvec, pr, pe, srel, sent);
  k_neighbor<<<8202, 256, 0, stream>>>(q_l1, q_l2, q_r1, q_r2, s_l1, s_l2, s_r1, s_r2,
                                       pr, pe, srel, sent, gcn_wb, gcn_b, hop_gate,
                                       qn, sn, XX);
  k_sup1<<<40, 256, 0, stream>>>(sn, p1_w, p1_b, h1b);
  k_sup2<<<5, 256, 0, stream>>>(sn, h1b, p2_w, p2_b, ln_g, ln_b, sg);
  k_sg2<<<32, 256, 0, stream>>>(sg, w_hh, WWb, sm);

  for (int step = 0; step < 4; ++step) {
    if (step == 0)
      k_gates_mfma<<<448, 256, 0, stream>>>(XX, WWa, bsum, gates, 8);
    else
      k_gates_mfma<<<448, 256, 0, stream>>>(XX, WWb, bsum, gates, 17);
    k_cell<<<4096, 256, 0, stream>>>(gates, qn, cbuf, XX, sg, sm, (float*)d_out, step);
  }
}

// Round 18
// 328.699 us; speedup vs baseline: 1.1179x; 1.0235x over previous
//
#include <hip/hip_runtime.h>

typedef unsigned short bf16u;
typedef unsigned char u8;
typedef unsigned int u32;
typedef float f32x4 __attribute__((ext_vector_type(4)));
typedef short bf16x8 __attribute__((ext_vector_type(8)));

__device__ inline float sigmoidf_(float x) { return 1.f / (1.f + __expf(-x)); }
__device__ inline float b2f(bf16u u) { return __uint_as_float(((u32)u) << 16); }
__device__ inline bf16u f2b(float f) {
  u32 i = __float_as_uint(f);
  u32 r = (i + 0x7fffu + ((i >> 16) & 1u)) >> 16;
  return (bf16u)r;
}
// uint8 table codec: stored = clamp(round(v*512 + 128)); decoded = u/512 - 0.25
__device__ inline u8 enc8(float v) {
  float q = fmaf(v, 512.f, 128.5f);
  q = fminf(fmaxf(q, 0.f), 255.f);
  return (u8)(int)q;
}
__device__ inline float ub0(u32 u) { return (float)(u & 0xffu); }
__device__ inline float ub1(u32 u) { return (float)((u >> 8) & 0xffu); }
__device__ inline float ub2(u32 u) { return (float)((u >> 16) & 0xffu); }
__device__ inline float ub3(u32 u) { return (float)(u >> 24); }

// ---------------------------------------------------------------------------
// Fused prep: XX pad zero (all 4096 blocks), LSTM weight pack (b<2048),
// Vp bf16 conversion (b in [2048,2304)), uvec (b==2304).
__global__ __launch_bounds__(256) void k_prep(
    const float* __restrict__ gcn_w, const float* __restrict__ attn_w,
    const float* __restrict__ w_ih, const float* __restrict__ w_hh,
    const float* __restrict__ b_ih, const float* __restrict__ b_hh,
    bf16u* __restrict__ Vp, float* __restrict__ uvec,
    bf16u* __restrict__ WWa, bf16u* __restrict__ WWb, float* __restrict__ bsum,
    bf16u* __restrict__ XX)
{
  const int b = blockIdx.x, t = threadIdx.x;
  if (t < 59) XX[(size_t)b * 576 + 517 + t] = 0;
  if (b < 2048) {
    float wi = w_ih[b * 256 + t];
    float wh = w_hh[b * 512 + t];
    WWa[(size_t)b * 576 + t] = f2b(wi);
    WWb[(size_t)b * 576 + t] = f2b(wi + wh);
    WWb[(size_t)b * 576 + 256 + t] = f2b(wh);
    if (t < 59) WWb[(size_t)b * 576 + 517 + t] = 0;
    if (t == 0) bsum[b] = b_ih[b] + b_hh[b];
  } else if (b < 2304) {
    const int o = b - 2048;
    if (t < 128) Vp[o * 128 + t] = f2b(gcn_w[(o & 127) * 256 + ((o >> 7) << 7) + t]);
  } else if (b == 2304) {
    const int col = ((t >> 7) << 7) + (t & 127);
    float acc = 0.f;
    for (int d = 0; d < 128; ++d) acc += gcn_w[d * 256 + col] * attn_w[d];
    uvec[t] = acc;
  }
}

// ---------------------------------------------------------------------------
// pr/pe tables (uint8) via bf16 MFMA; scores post-staging from LDS.
__global__ __launch_bounds__(256) void k_pre_gemm(
    const float* __restrict__ emb, const bf16u* __restrict__ Vp,
    const float* __restrict__ uvec,
    u8* __restrict__ pr, u8* __restrict__ pe,
    float* __restrict__ srel, float* __restrict__ sent)
{
  const int t = threadIdx.x;
  const int row0 = blockIdx.x << 6;
  __shared__ short As[64][136];
  __shared__ union PB {
    short B[128][136];
    u8 ob[64][272];
  } pb;
  __shared__ float us[256];
  us[t] = uvec[t];
  {
    const uint4* src = (const uint4*)Vp;
    #pragma unroll
    for (int s = 0; s < 8; ++s) {
      int f = s * 256 + t;
      *(uint4*)&pb.B[f >> 4][(f & 15) * 8] = src[f];
    }
  }
  #pragma unroll
  for (int s = 0; s < 8; ++s) {
    int f = s * 256 + t;
    int row = f >> 5, q = f & 31;
    int gr = row0 + row; if (gr > 100000) gr = 100000;
    float4 v = *(const float4*)&emb[(size_t)gr * 128 + (q << 2)];
    ushort4 pk;
    pk.x = f2b(v.x); pk.y = f2b(v.y); pk.z = f2b(v.z); pk.w = f2b(v.w);
    *(ushort4*)&As[row][q << 2] = pk;
  }
  __syncthreads();
  {
    const int row = t >> 2, l = t & 3;
    int gr = row0 + row; if (gr > 100000) gr = 100000;
    const short* ar = &As[row][l * 32];
    const float* u0 = &us[l * 32];
    const float* u1 = &us[128 + l * 32];
    float p0 = 0.f, p1 = 0.f;
    #pragma unroll
    for (int i = 0; i < 32; ++i) {
      float e = __uint_as_float(((u32)(unsigned short)ar[i]) << 16);
      p0 += e * u0[i];
      p1 += e * u1[i];
    }
    p0 += __shfl_xor(p0, 1, 64); p0 += __shfl_xor(p0, 2, 64);
    p1 += __shfl_xor(p1, 1, 64); p1 += __shfl_xor(p1, 2, 64);
    if (l == 0) { srel[gr] = p0; sent[gr] = p1; }
  }
  const int wave = t >> 6, lane = t & 63;
  const int quad = lane >> 4, l16 = lane & 15;
  const int wm = (wave >> 1) << 5, wn = (wave & 1) << 6;
  f32x4 acc0[2][4], acc1[2][4];
  #pragma unroll
  for (int i = 0; i < 2; ++i)
    #pragma unroll
    for (int j = 0; j < 4; ++j) {
      acc0[i][j] = (f32x4){0.f, 0.f, 0.f, 0.f};
      acc1[i][j] = (f32x4){0.f, 0.f, 0.f, 0.f};
    }
  #pragma unroll
  for (int kc = 0; kc < 4; ++kc) {
    bf16x8 af[2], bfr[4];
    #pragma unroll
    for (int i = 0; i < 2; ++i)
      af[i] = *(const bf16x8*)&As[wm + i * 16 + l16][kc * 32 + quad * 8];
    #pragma unroll
    for (int j = 0; j < 4; ++j)
      bfr[j] = *(const bf16x8*)&pb.B[wn + j * 16 + l16][kc * 32 + quad * 8];
    #pragma unroll
    for (int i = 0; i < 2; ++i)
      #pragma unroll
      for (int j = 0; j < 4; ++j)
        acc0[i][j] = __builtin_amdgcn_mfma_f32_16x16x32_bf16(af[i], bfr[j], acc0[i][j], 0, 0, 0);
  }
  __syncthreads();
  {
    const uint4* src = (const uint4*)(Vp + 128 * 128);
    #pragma unroll
    for (int s = 0; s < 8; ++s) {
      int f = s * 256 + t;
      *(uint4*)&pb.B[f >> 4][(f & 15) * 8] = src[f];
    }
  }
  __syncthreads();
  #pragma unroll
  for (int kc = 0; kc < 4; ++kc) {
    bf16x8 af[2], bfr[4];
    #pragma unroll
    for (int i = 0; i < 2; ++i)
      af[i] = *(const bf16x8*)&As[wm + i * 16 + l16][kc * 32 + quad * 8];
    #pragma unroll
    for (int j = 0; j < 4; ++j)
      bfr[j] = *(const bf16x8*)&pb.B[wn + j * 16 + l16][kc * 32 + quad * 8];
    #pragma unroll
    for (int i = 0; i < 2; ++i)
      #pragma unroll
      for (int j = 0; j < 4; ++j)
        acc1[i][j] = __builtin_amdgcn_mfma_f32_16x16x32_bf16(af[i], bfr[j], acc1[i][j], 0, 0, 0);
  }
  __syncthreads();
  #pragma unroll
  for (int j = 0; j < 4; ++j) {
    const int col = wn + j * 16 + l16;
    #pragma unroll
    for (int i = 0; i < 2; ++i) {
      #pragma unroll
      for (int r = 0; r < 4; ++r) {
        int row = wm + i * 16 + quad * 4 + r;
        pb.ob[row][col] = enc8(acc0[i][j][r]);
        pb.ob[row][128 + col] = enc8(acc1[i][j][r]);
      }
    }
  }
  __syncthreads();
  #pragma unroll
  for (int s = 0; s < 4; ++s) {
    int c = s * 256 + t;
    int row = c >> 4, part = c & 15;
    int gr = row0 + row;
    if (gr <= 100000) {
      uint4 v = *(const uint4*)&pb.ob[row][part * 16];
      if (part < 8) *(uint4*)&pr[(size_t)gr * 128 + part * 16] = v;
      else          *(uint4*)&pe[(size_t)gr * 128 + (part - 8) * 16] = v;
    }
  }
}

// ---------------------------------------------------------------------------
// Merged neighbor encoder with uint8 tables.
__global__ __launch_bounds__(256) void k_neighbor(
    const int* __restrict__ q_l1, const int* __restrict__ q_l2,
    const int* __restrict__ q_r1, const int* __restrict__ q_r2,
    const int* __restrict__ s_l1, const int* __restrict__ s_l2,
    const int* __restrict__ s_r1, const int* __restrict__ s_r2,
    const u8* __restrict__ pr, const u8* __restrict__ pe,
    const float* __restrict__ srel, const float* __restrict__ sent,
    const float* __restrict__ gcn_wb, const float* __restrict__ gcn_b,
    const float* __restrict__ hop_gate,
    float* __restrict__ qn, float* __restrict__ sn, bf16u* __restrict__ XX)
{
  const int b = blockIdx.x, t = threadIdx.x;
  const int *cA, *cB; float* outp; bf16u* xxp; int n, coloff;
  if (b < 4096)      { cA = q_l1; cB = q_l2; n = b;        outp = qn; xxp = XX; coloff = 0; }
  else if (b < 8192) { cA = q_r1; cB = q_r2; n = b - 4096; outp = qn; xxp = XX; coloff = 128; }
  else if (b < 8197) { cA = s_l1; cB = s_l2; n = b - 8192; outp = sn; xxp = 0;  coloff = 0; }
  else               { cA = s_r1; cB = s_r2; n = b - 8197; outp = sn; xxp = 0;  coloff = 128; }
  __shared__ int idxA[64][2], idxB[64][2];
  __shared__ float wA[64], wB[64];
  __shared__ float red[2][8][16][8];
  if (t < 128) {
    const int hop = t >> 6, nn = t & 63;
    const int* conn = hop ? cB : cA;
    int rel = conn[(n * 64 + nn) * 2 + 0];
    int ent = conn[(n * 64 + nn) * 2 + 1];
    int (*idx)[2] = hop ? idxB : idxA;
    idx[nn][0] = rel; idx[nn][1] = ent;
    float sc = srel[rel] + sent[ent];
    float m = sc;
    #pragma unroll
    for (int off = 32; off; off >>= 1) m = fmaxf(m, __shfl_xor(m, off, 64));
    float e = __expf(sc - m);
    float s = e;
    #pragma unroll
    for (int off = 32; off; off >>= 1) s += __shfl_xor(s, off, 64);
    (hop ? wB : wA)[nn] = e / s;
  }
  __syncthreads();
  {
    const int hop = t >> 7, g = (t >> 4) & 7, p = t & 15;
    const int (*idx)[2] = hop ? idxB : idxA;
    const float* w = hop ? wB : wA;
    uint2 ra[8], rb[8];
    #pragma unroll
    for (int kk = 0; kk < 8; ++kk) {
      int k = g + (kk << 3);
      ra[kk] = *(const uint2*)&pr[(size_t)idx[k][0] * 128 + p * 8];
      rb[kk] = *(const uint2*)&pe[(size_t)idx[k][1] * 128 + p * 8];
    }
    float a[8];
    #pragma unroll
    for (int c = 0; c < 8; ++c) a[c] = 0.f;
    #pragma unroll
    for (int kk = 0; kk < 8; ++kk) {
      float wk = w[g + (kk << 3)];
      a[0] += wk * (ub0(ra[kk].x) + ub0(rb[kk].x));
      a[1] += wk * (ub1(ra[kk].x) + ub1(rb[kk].x));
      a[2] += wk * (ub2(ra[kk].x) + ub2(rb[kk].x));
      a[3] += wk * (ub3(ra[kk].x) + ub3(rb[kk].x));
      a[4] += wk * (ub0(ra[kk].y) + ub0(rb[kk].y));
      a[5] += wk * (ub1(ra[kk].y) + ub1(rb[kk].y));
      a[6] += wk * (ub2(ra[kk].y) + ub2(rb[kk].y));
      a[7] += wk * (ub3(ra[kk].y) + ub3(rb[kk].y));
    }
    *(float4*)&red[hop][g][p][0] = (float4){a[0], a[1], a[2], a[3]};
    *(float4*)&red[hop][g][p][4] = (float4){a[4], a[5], a[6], a[7]};
  }
  __syncthreads();
  if (t < 128) {
    const int d = t, p = d >> 3, cq = d & 7;
    float sA = 0.f, sB = 0.f;
    #pragma unroll
    for (int g = 0; g < 8; ++g) {
      sA += red[0][g][p][cq];
      sB += red[1][g][p][cq];
    }
    float accA = sA * (1.f / 512.f) - 0.5f;
    float accB = sB * (1.f / 512.f) - 0.5f;
    float bias = gcn_wb[d] + gcn_b[d];
    float g0 = hop_gate[0], g1 = hop_gate[1];
    float mx = fmaxf(g0, g1);
    float e0 = __expf(g0 - mx), e1 = __expf(g1 - mx);
    float inv = 1.f / (e0 + e1);
    float v = e0 * inv * tanhf(bias + accA) + e1 * inv * tanhf(bias + accB);
    outp[n * 256 + coloff + d] = v;
    if (xxp) xxp[(size_t)n * 576 + coloff + d] = f2b(v);
  }
}

// ---------------------------------------------------------------------------
__global__ __launch_bounds__(256) void k_sup1(
    const float* __restrict__ sn, const float* __restrict__ p1_w,
    const float* __restrict__ p1_b, float* __restrict__ h1)
{
  const int r = blockIdx.x >> 3, j0 = (blockIdx.x & 7) << 6;
  const int t = threadIdx.x;
  __shared__ float xs[256];
  xs[t] = sn[r * 256 + t];
  __syncthreads();
  const int j = j0 + (t >> 2), q = t & 3;
  const float* wr = p1_w + (size_t)j * 256 + q * 64;
  float acc = 0.f;
  #pragma unroll
  for (int k = 0; k < 64; ++k) acc += xs[q * 64 + k] * wr[k];
  acc += __shfl_xor(acc, 1, 64);
  acc += __shfl_xor(acc, 2, 64);
  if (q == 0) h1[r * 512 + j] = fmaxf(acc + p1_b[j], 0.f);
}

__global__ __launch_bounds__(256) void k_sup2(
    const float* __restrict__ sn, const float* __restrict__ h1,
    const float* __restrict__ p2_w, const float* __restrict__ p2_b,
    const float* __restrict__ ln_g, const float* __restrict__ ln_b,
    float* __restrict__ sg)
{
  const int r = blockIdx.x, t = threadIdx.x;
  const int lane = t & 63, wave = t >> 6;
  __shared__ float hs[512];
  __shared__ float zs[256];
  __shared__ float r1[4], r2[4];
  hs[t] = h1[r * 512 + t];
  hs[t + 256] = h1[r * 512 + 256 + t];
  __syncthreads();
  const int q = t & 3;
  #pragma unroll
  for (int jc = 0; jc < 4; ++jc) {
    int j = jc * 64 + (t >> 2);
    const float* wr = p2_w + (size_t)j * 512 + q * 128;
    float acc = 0.f;
    #pragma unroll
    for (int k = 0; k < 128; ++k) acc += hs[q * 128 + k] * wr[k];
    acc += __shfl_xor(acc, 1, 64);
    acc += __shfl_xor(acc, 2, 64);
    if (q == 0) zs[j] = acc + p2_b[j] + sn[r * 256 + j];
  }
  __syncthreads();
  float v = zs[t];
  float s1 = v, s2 = v * v;
  #pragma unroll
  for (int off = 32; off; off >>= 1) { s1 += __shfl_xor(s1, off, 64); s2 += __shfl_xor(s2, off, 64); }
  if (lane == 0) { r1[wave] = s1; r2[wave] = s2; }
  __syncthreads();
  float S1 = r1[0] + r1[1] + r1[2] + r1[3];
  float S2 = r2[0] + r2[1] + r2[2] + r2[3];
  float mu = S1 * (1.f / 256.f);
  float var = S2 * (1.f / 256.f) - mu * mu;
  sg[r * 256 + t] = (v - mu) * rsqrtf(var + 1e-6f) * ln_g[t] + ln_b[t];
}

// ---------------------------------------------------------------------------
__global__ __launch_bounds__(256) void k_sg2(
    const float* __restrict__ sg, const float* __restrict__ w_hh,
    bf16u* __restrict__ WWb, float* __restrict__ sm)
{
  __shared__ float s[5][256];
  const int t = threadIdx.x;
  for (int i = t; i < 1280; i += 256) s[i >> 8][i & 255] = sg[i];
  __syncthreads();
  if (blockIdx.x == 0)
    sm[t] = (s[0][t] + s[1][t] + s[2][t] + s[3][t] + s[4][t]) * 0.2f;
  const int j = (blockIdx.x << 6) + (t >> 2), q = t & 3;
  const float4* wr = (const float4*)(w_hh + (size_t)j * 512 + 256 + q * 64);
  float a[5] = {0.f, 0.f, 0.f, 0.f, 0.f};
  #pragma unroll
  for (int kk = 0; kk < 16; ++kk) {
    float4 w = wr[kk];
    int k = q * 64 + kk * 4;
    #pragma unroll
    for (int r = 0; r < 5; ++r)
      a[r] += s[r][k] * w.x + s[r][k+1] * w.y + s[r][k+2] * w.z + s[r][k+3] * w.w;
  }
  #pragma unroll
  for (int r = 0; r < 5; ++r) {
    a[r] += __shfl_xor(a[r], 1, 64);
    a[r] += __shfl_xor(a[r], 2, 64);
  }
  if (q == 0) {
    #pragma unroll
    for (int r = 0; r < 5; ++r)
      WWb[(size_t)j * 576 + 512 + r] = f2b(a[r]);
  }
}

// ---------------------------------------------------------------------------
// gates (bf16, stride 2048, cols 0..1791) = XX @ WW.T + bsum, MFMA 16x16x32.
// r13 structure with DOUBLE-BUFFERED LDS: 1 barrier per K-iteration.
// 128x128 tile, 32-wide K chunks, register prefetch, scatter epilogue,
// XCD swizzle. Grid 448 (14 col panels).
__global__ __launch_bounds__(256) void k_gates_mfma(
    const bf16u* __restrict__ XX, const bf16u* __restrict__ WW,
    const float* __restrict__ bsum, bf16u* __restrict__ gates, int kchunks)
{
  const int t = threadIdx.x;
  const int wave = t >> 6, lane = t & 63;
  const int quad = lane >> 4, l16 = lane & 15;
  const int wm = (wave >> 1) << 6, wn = (wave & 1) << 6;
  const int lin = (blockIdx.x & 7) * 56 + (blockIdx.x >> 3);
  const int row0 = (lin / 14) << 7;
  const int col0 = (lin % 14) << 7;
  __shared__ short As[2][128][40];
  __shared__ short Bs[2][128][40];
  f32x4 acc[4][4];
  #pragma unroll
  for (int i = 0; i < 4; ++i)
    #pragma unroll
    for (int j = 0; j < 4; ++j) acc[i][j] = (f32x4){0.f, 0.f, 0.f, 0.f};

  const int srow = t >> 1, shalf = t & 1;
  const bf16u* xp = XX + (size_t)(row0 + srow) * 576 + shalf * 16;
  const bf16u* wp = WW + (size_t)(col0 + srow) * 576 + shalf * 16;

  // stage chunk 0 into buf 0
  {
    uint4 x0 = *(const uint4*)(xp);
    uint4 x1 = *(const uint4*)(xp + 8);
    uint4 w0 = *(const uint4*)(wp);
    uint4 w1 = *(const uint4*)(wp + 8);
    *(uint4*)&As[0][srow][shalf * 16] = x0;
    *(uint4*)&As[0][srow][shalf * 16 + 8] = x1;
    *(uint4*)&Bs[0][srow][shalf * 16] = w0;
    *(uint4*)&Bs[0][srow][shalf * 16 + 8] = w1;
  }
  // prefetch chunk 1 into registers
  uint4 x0, x1, w0, w1;
  if (kchunks > 1) {
    x0 = *(const uint4*)(xp + 32);
    x1 = *(const uint4*)(xp + 40);
    w0 = *(const uint4*)(wp + 32);
    w1 = *(const uint4*)(wp + 40);
  }
  __syncthreads();   // buf 0 visible

  for (int kc = 0; kc < kchunks; ++kc) {
    const int cur = kc & 1, nxt = cur ^ 1;
    // store prefetched chunk kc+1 into the other buffer (no reader conflict)
    if (kc + 1 < kchunks) {
      *(uint4*)&As[nxt][srow][shalf * 16] = x0;
      *(uint4*)&As[nxt][srow][shalf * 16 + 8] = x1;
      *(uint4*)&Bs[nxt][srow][shalf * 16] = w0;
      *(uint4*)&Bs[nxt][srow][shalf * 16 + 8] = w1;
    }
    // prefetch chunk kc+2
    if (kc + 2 < kchunks) {
      x0 = *(const uint4*)(xp + (kc+2) * 32);
      x1 = *(const uint4*)(xp + (kc+2) * 32 + 8);
      w0 = *(const uint4*)(wp + (kc+2) * 32);
      w1 = *(const uint4*)(wp + (kc+2) * 32 + 8);
    }
    // compute from current buffer
    bf16x8 af[4], bfr[4];
    #pragma unroll
    for (int i = 0; i < 4; ++i)
      af[i] = *(const bf16x8*)&As[cur][wm + i * 16 + l16][quad * 8];
    #pragma unroll
    for (int j = 0; j < 4; ++j)
      bfr[j] = *(const bf16x8*)&Bs[cur][wn + j * 16 + l16][quad * 8];
    #pragma unroll
    for (int i = 0; i < 4; ++i)
      #pragma unroll
      for (int j = 0; j < 4; ++j)
        acc[i][j] = __builtin_amdgcn_mfma_f32_16x16x32_bf16(af[i], bfr[j], acc[i][j], 0, 0, 0);
    // single barrier: makes nxt-buffer writes visible AND protects cur buffer
    // (overwritten at iter kc+2) until all reads this iter are done.
    __syncthreads();
  }

  #pragma unroll
  for (int j = 0; j < 4; ++j) {
    const int col = col0 + wn + j * 16 + l16;
    const float bs = bsum[col];
    #pragma unroll
    for (int i = 0; i < 4; ++i) {
      #pragma unroll
      for (int r = 0; r < 4; ++r) {
        int row = row0 + wm + i * 16 + quad * 4 + r;
        gates[(size_t)row * 2048 + col] = f2b(acc[i][j][r] + bs);
      }
    }
  }
}

// ---------------------------------------------------------------------------
// Cell pointwise + attention (fused 5-way reduction, 1 barrier).
// Step 3 skips the dead c-store.
__global__ __launch_bounds__(256) void k_cell(
    const bf16u* __restrict__ gates, const float* __restrict__ qn,
    float* __restrict__ c, bf16u* __restrict__ XX,
    const float* __restrict__ sg, const float* __restrict__ sm,
    float* __restrict__ out, int step)
{
  __shared__ float red[4][6];
  const int b = blockIdx.x, t = threadIdx.x;
  const int lane = t & 63, wave = t >> 6;
  const bf16u* g = gates + (size_t)b * 2048;
  float i0 = b2f(g[t]),       f0 = b2f(g[512 + t]), gg0 = b2f(g[1024 + t]), o0 = b2f(g[1536 + t]);
  float i1 = b2f(g[256 + t]), f1 = b2f(g[768 + t]), gg1 = b2f(g[1280 + t]);
  float co0 = step ? c[b * 512 + t] : 0.f;
  float co1 = step ? c[b * 512 + 256 + t] : 0.f;
  float c0 = sigmoidf_(f0) * co0 + sigmoidf_(i0) * tanhf(gg0);
  float c1 = sigmoidf_(f1) * co1 + sigmoidf_(i1) * tanhf(gg1);
  if (step < 3) {
    c[b * 512 + t] = c0;
    c[b * 512 + 256 + t] = c1;
  }
  float hcv = sigmoidf_(o0) * tanhf(c0);
  float h = qn[b * 256 + t] + hcv;
  if (step < 3) {
    XX[(size_t)b * 576 + 256 + t] = f2b(hcv);
    float dots[5];
    #pragma unroll
    for (int s = 0; s < 5; ++s) dots[s] = h * sg[s * 256 + t];
    #pragma unroll
    for (int off = 32; off; off >>= 1) {
      #pragma unroll
      for (int s = 0; s < 5; ++s) dots[s] += __shfl_xor(dots[s], off, 64);
    }
    if (lane == 0) {
      #pragma unroll
      for (int s = 0; s < 5; ++s) red[wave][s] = dots[s];
    }
    __syncthreads();
    #pragma unroll
    for (int s = 0; s < 5; ++s)
      dots[s] = red[0][s] + red[1][s] + red[2][s] + red[3][s];
    float m = dots[0];
    #pragma unroll
    for (int s = 1; s < 5; ++s) m = fmaxf(m, dots[s]);
    float sum = 0.f;
    #pragma unroll
    for (int s = 0; s < 5; ++s) sum += __expf(dots[s] - m);
    if (t < 5) {
      float dv = (t == 1) ? dots[1] : (t == 2) ? dots[2] : (t == 3) ? dots[3]
               : (t == 4) ? dots[4] : dots[0];
      XX[(size_t)b * 576 + 512 + t] = f2b(__expf(dv - m) / sum);
    }
  } else {
    float v = h * sm[t];
    #pragma unroll
    for (int off = 32; off; off >>= 1) v += __shfl_xor(v, off, 64);
    if (lane == 0) red[wave][0] = v;
    __syncthreads();
    if (t == 0) out[b] = red[0][0] + red[1][0] + red[2][0] + red[3][0];
  }
}

// ---------------------------------------------------------------------------
extern "C" void kernel_launch(void* const* d_in, const int* in_sizes, int n_in,
                              void* d_out, int out_size, void* d_ws, size_t ws_size,
                              hipStream_t stream)
{
  (void)in_sizes; (void)n_in; (void)out_size; (void)ws_size;
  const int *q_l1 = (const int*)d_in[0], *q_l2 = (const int*)d_in[1];
  const int *q_r1 = (const int*)d_in[2], *q_r2 = (const int*)d_in[3];
  const int *s_l1 = (const int*)d_in[4], *s_l2 = (const int*)d_in[5];
  const int *s_r1 = (const int*)d_in[6], *s_r2 = (const int*)d_in[7];
  const float* emb      = (const float*)d_in[12];
  const float* gcn_w    = (const float*)d_in[13];
  const float* gcn_wb   = (const float*)d_in[14];
  const float* gcn_b    = (const float*)d_in[15];
  const float* hop_gate = (const float*)d_in[16];
  const float* attn_w   = (const float*)d_in[17];
  const float* p1_w = (const float*)d_in[19];
  const float* p1_b = (const float*)d_in[20];
  const float* p2_w = (const float*)d_in[21];
  const float* p2_b = (const float*)d_in[22];
  const float* ln_g = (const float*)d_in[23];
  const float* ln_b = (const float*)d_in[24];
  const float* w_ih = (const float*)d_in[25];
  const float* w_hh = (const float*)d_in[26];
  const float* b_ih = (const float*)d_in[27];
  const float* b_hh = (const float*)d_in[28];

  char* base = (char*)d_ws;
  size_t off = 0;
  auto alloc = [&](size_t bytes) -> char* {
    char* r = base + off;
    off = (off + bytes + 255) & ~(size_t)255;
    return r;
  };
  u8* pr       = (u8*)alloc(100001ull * 128);
  u8* pe       = (u8*)alloc(100001ull * 128);
  float* srel  = (float*)alloc(100001ull * 4);
  float* sent  = (float*)alloc(100001ull * 4);
  float* uvec  = (float*)alloc(256 * 4);
  bf16u* Vp    = (bf16u*)alloc(256 * 128 * 2);
  float* qn    = (float*)alloc(4096ull * 256 * 4);
  float* sn    = (float*)alloc(5 * 256 * 4);
  float* sg    = (float*)alloc(5 * 256 * 4);
  float* sm    = (float*)alloc(256 * 4);
  float* h1b   = (float*)alloc(5 * 512 * 4);
  bf16u* XX    = (bf16u*)alloc(4096ull * 576 * 2);
  bf16u* WWa   = (bf16u*)alloc(2048ull * 576 * 2);
  bf16u* WWb   = (bf16u*)alloc(2048ull * 576 * 2);
  float* bsum  = (float*)alloc(2048 * 4);
  bf16u* gates = (bf16u*)alloc(4096ull * 2048 * 2);
  float* cbuf  = (float*)alloc(4096ull * 512 * 4);

  k_prep<<<4096, 256, 0, stream>>>(gcn_w, attn_w, w_ih, w_hh, b_ih, b_hh,
                                   Vp, uvec, WWa, WWb, bsum, XX);
  k_pre_gemm<<<1563, 256, 0, stream>>>(emb, Vp, uvec, pr, pe, srel, sent);
  k_neighbor<<<8202, 256, 0, stream>>>(q_l1, q_l2, q_r1, q_r2, s_l1, s_l2, s_r1, s_r2,
                                       pr, pe, srel, sent, gcn_wb, gcn_b, hop_gate,
                                       qn, sn, XX);
  k_sup1<<<40, 256, 0, stream>>>(sn, p1_w, p1_b, h1b);
  k_sup2<<<5, 256, 0, stream>>>(sn, h1b, p2_w, p2_b, ln_g, ln_b, sg);
  k_sg2<<<32, 256, 0, stream>>>(sg, w_hh, WWb, sm);

  for (int step = 0; step < 4; ++step) {
    if (step == 0)
      k_gates_mfma<<<448, 256, 0, stream>>>(XX, WWa, bsum, gates, 8);
    else
      k_gates_mfma<<<448, 256, 0, stream>>>(XX, WWb, bsum, gates, 17);
    k_cell<<<4096, 256, 0, stream>>>(gates, qn, cbuf, XX, sg, sm, (float*)d_out, step);
  }
}